// Round 1
// baseline (2601.161 us; speedup 1.0000x reference)
//
#include <hip/hip_runtime.h>

#define BB 64
#define TT 96
#define FF 32
#define HH 128
#define G4 512

#define LOG2E 1.4426950408889634f

__device__ __forceinline__ float fexp2(float x){ return __builtin_amdgcn_exp2f(x); }
__device__ __forceinline__ float frcp(float x){ return __builtin_amdgcn_rcpf(x); }
__device__ __forceinline__ float fsigmoid(float x){ return frcp(1.0f + fexp2(-LOG2E*x)); }
__device__ __forceinline__ float ftanh(float x){
    // tanh(x) = 1 - 2/(1+exp(2x)); saturates correctly at +-1
    float u = fexp2(2.0f*LOG2E*x);
    return 1.0f - 2.0f*frcp(1.0f + u);
}

// ---------------------------------------------------------------------------
// Kernel 1: fold fc_w/fc_b into dec_k:  G = fc_w[0:128]@dec_k,
// g_y = fc_w[128]@dec_k, g_b = fc_b@dec_k + dec_b
// ---------------------------------------------------------------------------
__global__ __launch_bounds__(256) void k_prep(const float* __restrict__ fc_w,
                                              const float* __restrict__ fc_b,
                                              const float* __restrict__ dec_k,
                                              const float* __restrict__ dec_b,
                                              float* __restrict__ Gm,
                                              float* __restrict__ gy,
                                              float* __restrict__ gb){
    int blk = blockIdx.x, tid = threadIdx.x;
    int u0 = tid, u1 = tid + 256;
    float a0 = 0.f, a1 = 0.f;
    if (blk < 128){
        for (int m = 0; m < 128; ++m){
            float w = fc_w[blk*128 + m];
            a0 += w * dec_k[m*G4 + u0];
            a1 += w * dec_k[m*G4 + u1];
        }
        Gm[blk*G4 + u0] = a0; Gm[blk*G4 + u1] = a1;
    } else if (blk == 128){
        for (int m = 0; m < 128; ++m){
            float w = fc_w[128*128 + m];
            a0 += w * dec_k[m*G4 + u0];
            a1 += w * dec_k[m*G4 + u1];
        }
        gy[u0] = a0; gy[u1] = a1;
    } else {
        for (int m = 0; m < 128; ++m){
            float w = fc_b[m];
            a0 += w * dec_k[m*G4 + u0];
            a1 += w * dec_k[m*G4 + u1];
        }
        gb[u0] = a0 + dec_b[u0]; gb[u1] = a1 + dec_b[u1];
    }
}

// ---------------------------------------------------------------------------
// Kernel 2: encoder. One block per batch. 96 sequential steps.
// LDS: W1T (ae_w1 rows 0..255, transposed, row stride 260) + xproj + state.
// Regs: enc_k/enc_r columns (u=tid, tid+256).
// ---------------------------------------------------------------------------
__global__ __launch_bounds__(256) void k_enc(const float* __restrict__ inputs,
                                             const float* __restrict__ enc_k,
                                             const float* __restrict__ enc_r,
                                             const float* __restrict__ enc_b,
                                             const float* __restrict__ ae_w1,
                                             const float* __restrict__ ae_b1,
                                             const float* __restrict__ ae_w2,
                                             float* __restrict__ ws_xenc){
    extern __shared__ float lds[];
    float* W1T = lds;              // [128][260]  (33280)
    float* XPJ = lds + 33280;      // [32][128]
    float* HST = lds + 37376;      // 256: h(0..127), s(128..255)
    float* PE  = lds + 37632;      // 128
    float* EF  = lds + 37760;      // 32
    float* XT  = lds + 37792;      // 32
    float* PP  = lds + 37824;      // 256 partials
    float* IG  = lds + 38080;      // 128

    const int b = blockIdx.x, tid = threadIdx.x;
    const float* xin = inputs + b*TT*FF;

    // build transposed W1hs in LDS
    {
        int j = tid & 127, kh = tid >> 7;
        for (int kk = 0; kk < 128; ++kk){
            int k = kh*128 + kk;
            W1T[j*260 + k] = ae_w1[k*128 + j];
        }
    }
    HST[tid] = 0.f;

    // xproj[f][j] = sum_t x[t][f] * ae_w1[(256+t)*128 + j]  (time-invariant)
    {
        int j = tid & 127, fh = tid >> 7;
        float acc[16];
        #pragma unroll
        for (int i = 0; i < 16; ++i) acc[i] = 0.f;
        for (int t = 0; t < TT; ++t){
            float w = ae_w1[(256+t)*128 + j];
            #pragma unroll
            for (int i = 0; i < 16; ++i) acc[i] += xin[t*FF + fh*16 + i] * w;
        }
        #pragma unroll
        for (int i = 0; i < 16; ++i) XPJ[(fh*16 + i)*128 + j] = acc[i];
    }

    // register-cache LSTM weight columns u0=tid, u1=tid+256
    float ka0[32], ka1[32], ra0[128], ra1[128];
    #pragma unroll
    for (int f2 = 0; f2 < 32; ++f2){ ka0[f2] = enc_k[f2*G4 + tid]; ka1[f2] = enc_k[f2*G4 + tid + 256]; }
    #pragma unroll
    for (int k = 0; k < 128; ++k){ ra0[k] = enc_r[k*G4 + tid]; ra1[k] = enc_r[k*G4 + tid + 256]; }
    __syncthreads();

    for (int t = 0; t < TT; ++t){
        float xval = (tid < 32) ? xin[t*FF + tid] : 0.f;

        // PH-A: pe[j] = ae_b1[j] + sum_k [h;s][k] * W1hs[k][j]
        {
            int j = tid & 127, seg = tid >> 7;
            const float* wr = &W1T[j*260 + seg*128];
            const float* hs = &HST[seg*128];
            float a = 0.f;
            #pragma unroll
            for (int k = 0; k < 128; k += 4){
                float4 w4 = *(const float4*)(wr + k);
                float4 h4 = *(const float4*)(hs + k);
                a += w4.x*h4.x + w4.y*h4.y + w4.z*h4.z + w4.w*h4.w;
            }
            PP[seg*128 + j] = a;
        }
        __syncthreads();
        if (tid < 128) PE[tid] = PP[tid] + PP[128 + tid] + ae_b1[tid];
        __syncthreads();

        // PH-B: e[f] = sum_j tanh(pe[j] + xproj[f][j]) * ae_w2[j]
        {
            int f = tid >> 3, jseg = tid & 7;
            const float* xp = &XPJ[f*128 + jseg*16];
            const float* pe = &PE[jseg*16];
            float acc = 0.f;
            #pragma unroll
            for (int i = 0; i < 16; ++i) acc += ftanh(pe[i] + xp[i]) * ae_w2[jseg*16 + i];
            acc += __shfl_down(acc, 4, 8);
            acc += __shfl_down(acc, 2, 8);
            acc += __shfl_down(acc, 1, 8);
            if (jseg == 0) EF[f] = acc;
        }
        __syncthreads();

        // PH-C: softmax over 32 features, x_tilde = alpha * x_t
        if (tid < 32){
            float e = EF[tid], m = e;
            #pragma unroll
            for (int d = 16; d; d >>= 1) m = fmaxf(m, __shfl_xor(m, d, 32));
            float p = fexp2((e - m)*LOG2E);
            float ss = p;
            #pragma unroll
            for (int d = 16; d; d >>= 1) ss += __shfl_xor(ss, d, 32);
            XT[tid] = p * frcp(ss) * xval;
        }
        __syncthreads();

        // PH-D: z[u] = enc_b[u] + x_tilde@enc_k + h@enc_r   (u0=tid, u1=tid+256)
        float z0 = enc_b[tid], z1 = enc_b[tid + 256];
        #pragma unroll
        for (int f2 = 0; f2 < 32; f2 += 4){
            float4 x4 = *(const float4*)&XT[f2];
            z0 += x4.x*ka0[f2] + x4.y*ka0[f2+1] + x4.z*ka0[f2+2] + x4.w*ka0[f2+3];
            z1 += x4.x*ka1[f2] + x4.y*ka1[f2+1] + x4.z*ka1[f2+2] + x4.w*ka1[f2+3];
        }
        #pragma unroll
        for (int k = 0; k < 128; k += 4){
            float4 h4 = *(const float4*)&HST[k];
            z0 += h4.x*ra0[k] + h4.y*ra0[k+1] + h4.z*ra0[k+2] + h4.w*ra0[k+3];
            z1 += h4.x*ra1[k] + h4.y*ra1[k+1] + h4.z*ra1[k+2] + h4.w*ra1[k+3];
        }

        // PH-E: gates. tid<128 holds (i,g) for j=tid; tid>=128 holds (f,o) for j=tid-128
        if (tid < 128) IG[tid] = fsigmoid(z0) * ftanh(z1);
        __syncthreads();
        if (tid >= 128){
            int j = tid - 128;
            float cn = fsigmoid(z0) * HST[128 + j] + IG[j];
            float hn = fsigmoid(z1) * ftanh(cn);
            HST[128 + j] = cn;
            HST[j] = hn;
            ws_xenc[(b*TT + t)*HH + j] = hn;
        }
        __syncthreads();
    }
}

// ---------------------------------------------------------------------------
// Kernel 3: xeprojT[b][j][t] = sum_k x_enc[b][t][k] * ad_w1[(256+k)*128 + j]
// stored transposed so the decoder's tanh phase reads coalesced along t.
// ---------------------------------------------------------------------------
__global__ __launch_bounds__(256) void k_xept(const float* __restrict__ ws_xenc,
                                              const float* __restrict__ ad_w1,
                                              float* __restrict__ ws_xept){
    int b = blockIdx.x, q = blockIdx.y, tid = threadIdx.x;
    int j = tid & 127, th = tid >> 7;
    const float* xb = ws_xenc + b*TT*HH;
    float acc[12];
    #pragma unroll
    for (int i = 0; i < 12; ++i) acc[i] = 0.f;
    for (int k = 0; k < 128; ++k){
        float w = ad_w1[(256 + k)*128 + j];
        #pragma unroll
        for (int i = 0; i < 12; ++i){
            int tp = q*24 + th*12 + i;
            acc[i] += xb[tp*HH + k] * w;   // wave-uniform address -> scalar load
        }
    }
    #pragma unroll
    for (int i = 0; i < 12; ++i){
        int tp = q*24 + th*12 + i;
        ws_xept[(b*128 + j)*TT + tp] = acc[i];
    }
}

// ---------------------------------------------------------------------------
// Kernel 4: decoder. One block per batch. 96 sequential steps + output.
// Regs: W1dc (attention d/c weights) + G columns. LDS: x_enc, dec_r rows 0..51.
// dec_r rows 52..127 streamed from L2 each step.
// ---------------------------------------------------------------------------
__global__ __launch_bounds__(256) void k_dec(const float* __restrict__ inputs,
                                             const float* __restrict__ dec_r,
                                             const float* __restrict__ ad_w1,
                                             const float* __restrict__ ad_b1,
                                             const float* __restrict__ ad_w2,
                                             const float* __restrict__ ff_w,
                                             const float* __restrict__ ff_b,
                                             const float* __restrict__ Gm,
                                             const float* __restrict__ gy,
                                             const float* __restrict__ gb,
                                             const float* __restrict__ ws_xenc,
                                             const float* __restrict__ ws_xept,
                                             float* __restrict__ out){
    extern __shared__ float lds[];
    float* XE   = lds;             // [96][129] = 12384
    float* DRL  = lds + 12384;     // [52][512] = 26624 -> 39008
    float* DST  = lds + 39008;     // 256: d(0..127), c(128..255)
    float* APJ  = lds + 39264;     // 128
    float* PP2  = lds + 39392;     // 256 partials / ig buffer
    float* E96  = lds + 39648;     // 96
    float* BETA = lds + 39744;     // 96 (unnormalized)
    float* SCAL = lds + 39840;     // [0]=1/sum, [1]=y_t
    float* CTX  = lds + 39848;     // 128

    const int b = blockIdx.x, tid = threadIdx.x;

    for (int i = tid; i < TT*HH; i += 256)
        XE[(i >> 7)*129 + (i & 127)] = ws_xenc[b*TT*HH + i];
    for (int i = tid; i < 52*G4; i += 256) DRL[i] = dec_r[i];
    DST[tid] = 0.f;

    // register-cache attention weights (k-range by seg) and G columns
    float wdc[128], gc0[128], gc1[128];
    {
        int j = tid & 127, seg = tid >> 7;
        #pragma unroll
        for (int kk = 0; kk < 128; ++kk) wdc[kk] = ad_w1[(seg*128 + kk)*128 + j];
    }
    #pragma unroll
    for (int k = 0; k < 128; ++k){ gc0[k] = Gm[k*G4 + tid]; gc1[k] = Gm[k*G4 + tid + 256]; }
    __syncthreads();

    const float* xeptb = ws_xept + b*128*TT;

    for (int t = 0; t < TT; ++t){
        if (tid == 0) SCAL[1] = inputs[b*TT*FF + t*FF + (FF - 1)];

        // PH-1: attproj partial = sum_k [d;c][k]*W1dc[k][j]
        {
            int j = tid & 127, seg = tid >> 7;
            float a = 0.f;
            #pragma unroll
            for (int kk = 0; kk < 128; kk += 4){
                float4 d4 = *(const float4*)&DST[seg*128 + kk];
                a += d4.x*wdc[kk] + d4.y*wdc[kk+1] + d4.z*wdc[kk+2] + d4.w*wdc[kk+3];
            }
            PP2[seg*128 + j] = a;
        }

        // PH-5a: z contribution from d@dec_r (only needs DST; overlaps stream)
        float z0 = gb[tid], z1 = gb[tid + 256];
        #pragma unroll 4
        for (int k = 0; k < 52; ++k){
            float dv = DST[k];
            z0 += dv * DRL[k*G4 + tid];
            z1 += dv * DRL[k*G4 + tid + 256];
        }
        #pragma unroll 4
        for (int k = 52; k < 128; ++k){
            float dv = DST[k];
            z0 += dv * dec_r[k*G4 + tid];
            z1 += dv * dec_r[k*G4 + tid + 256];
        }
        __syncthreads();
        if (tid < 128) APJ[tid] = PP2[tid] + PP2[128 + tid] + ad_b1[tid];
        __syncthreads();

        // PH-2: e[t'] = sum_j tanh(attproj[j] + xeproj[t'][j]) * ad_w2[j]
        {
            int tp = tid & 127, jh = tid >> 7;
            float acc = 0.f;
            if (tp < 96){
                const float* xrow = xeptb + (jh*64)*TT + tp;
                #pragma unroll
                for (int jj = 0; jj < 64; ++jj)
                    acc += ftanh(APJ[jh*64 + jj] + xrow[jj*TT]) * ad_w2[jh*64 + jj];
            }
            PP2[jh*128 + tp] = acc;
        }
        __syncthreads();
        if (tid < 96) E96[tid] = PP2[tid] + PP2[128 + tid];
        __syncthreads();

        // PH-3: softmax over 96 timesteps (unnormalized; 1/sum folded later)
        if (tid < 64){
            float v  = E96[tid];
            float v2 = (tid < 32) ? E96[64 + tid] : -3.0e38f;
            float m = fmaxf(v, v2);
            #pragma unroll
            for (int d = 32; d; d >>= 1) m = fmaxf(m, __shfl_xor(m, d, 64));
            float p  = fexp2((v - m)*LOG2E);
            float p2 = (tid < 32) ? fexp2((v2 - m)*LOG2E) : 0.f;
            float ss = p + p2;
            #pragma unroll
            for (int d = 32; d; d >>= 1) ss += __shfl_xor(ss, d, 64);
            BETA[tid] = p;
            if (tid < 32) BETA[64 + tid] = p2;
            if (tid == 0) SCAL[0] = frcp(ss);
        }
        __syncthreads();

        // PH-4: ctx[k] = (sum_t beta[t]*x_enc[t][k]) / sum
        {
            int k = tid & 127, th = tid >> 7;
            float a = 0.f;
            #pragma unroll 8
            for (int i = 0; i < 48; ++i){
                int tp = th*48 + i;
                a += BETA[tp] * XE[tp*129 + k];
            }
            PP2[th*128 + k] = a;
        }
        __syncthreads();
        if (tid < 128) CTX[tid] = (PP2[tid] + PP2[128 + tid]) * SCAL[0];
        __syncthreads();

        // PH-5b: z += ctx@G + y_t*g_y
        {
            float yt = SCAL[1];
            z0 += yt * gy[tid];
            z1 += yt * gy[tid + 256];
            #pragma unroll
            for (int k = 0; k < 128; k += 4){
                float4 c4 = *(const float4*)&CTX[k];
                z0 += c4.x*gc0[k] + c4.y*gc0[k+1] + c4.z*gc0[k+2] + c4.w*gc0[k+3];
                z1 += c4.x*gc1[k] + c4.y*gc1[k+1] + c4.z*gc1[k+2] + c4.w*gc1[k+3];
            }
        }

        // PH-6: gates
        if (tid < 128) PP2[tid] = fsigmoid(z0) * ftanh(z1);   // i*g
        __syncthreads();
        if (tid >= 128){
            int j = tid - 128;
            float cn = fsigmoid(z0) * DST[128 + j] + PP2[j];
            float hn = fsigmoid(z1) * ftanh(cn);
            DST[128 + j] = cn;
            DST[j] = hn;
        }
        __syncthreads();
    }

    // output: y_pred = [d_n, ctx] @ ff_w + ff_b
    {
        int jp = tid & 31, seg = tid >> 5;
        float a = 0.f;
        #pragma unroll
        for (int kk = 0; kk < 32; ++kk){
            int k = seg*32 + kk;
            float val = (k < 128) ? DST[k] : CTX[k - 128];
            a += val * ff_w[k*FF + jp];
        }
        PP2[seg*32 + jp] = a;
    }
    __syncthreads();
    if (tid < 32){
        float o = ff_b[tid];
        #pragma unroll
        for (int s8 = 0; s8 < 8; ++s8) o += PP2[s8*32 + tid];
        out[b*FF + tid] = o;
    }
}

// ---------------------------------------------------------------------------
extern "C" void kernel_launch(void* const* d_in, const int* in_sizes, int n_in,
                              void* d_out, int out_size, void* d_ws, size_t ws_size,
                              hipStream_t stream) {
    const float* inputs = (const float*)d_in[0];
    const float* enc_k  = (const float*)d_in[1];
    const float* enc_r  = (const float*)d_in[2];
    const float* enc_b  = (const float*)d_in[3];
    const float* ae_w1  = (const float*)d_in[4];
    const float* ae_b1  = (const float*)d_in[5];
    const float* ae_w2  = (const float*)d_in[6];
    // d_in[7] = ae_b2 (softmax-invariant, unused)
    const float* dec_k  = (const float*)d_in[8];
    const float* dec_r  = (const float*)d_in[9];
    const float* dec_b  = (const float*)d_in[10];
    const float* ad_w1  = (const float*)d_in[11];
    const float* ad_b1  = (const float*)d_in[12];
    const float* ad_w2  = (const float*)d_in[13];
    // d_in[14] = ad_b2 (softmax-invariant, unused)
    const float* fc_w   = (const float*)d_in[15];
    const float* fc_b   = (const float*)d_in[16];
    const float* ff_w   = (const float*)d_in[17];
    const float* ff_b   = (const float*)d_in[18];

    float* ws      = (float*)d_ws;
    float* ws_xenc = ws;                 // 64*96*128
    float* ws_xept = ws + 786432;        // 64*128*96
    float* Gm      = ws + 1572864;       // 128*512
    float* gy      = ws + 1638400;       // 512
    float* gb      = ws + 1638912;       // 512

    // opt-in for >64KB dynamic LDS (idempotent, host-side, capture-safe)
    hipFuncSetAttribute((const void*)k_enc, hipFuncAttributeMaxDynamicSharedMemorySize, 152832);
    hipFuncSetAttribute((const void*)k_dec, hipFuncAttributeMaxDynamicSharedMemorySize, 159904);

    k_prep<<<130, 256, 0, stream>>>(fc_w, fc_b, dec_k, dec_b, Gm, gy, gb);
    k_enc<<<64, 256, 152832, stream>>>(inputs, enc_k, enc_r, enc_b, ae_w1, ae_b1, ae_w2, ws_xenc);
    k_xept<<<dim3(64, 4), 256, 0, stream>>>(ws_xenc, ad_w1, ws_xept);
    k_dec<<<64, 256, 159904, stream>>>(inputs, dec_r, ad_w1, ad_b1, ad_w2, ff_w, ff_b,
                                       Gm, gy, gb, ws_xenc, ws_xept, (float*)d_out);
}

// Round 2
// 2290.907 us; speedup vs baseline: 1.1354x; 1.1354x over previous
//
#include <hip/hip_runtime.h>

#define TT 96
#define FF 32
#define HH 128
#define G4 512
#define LOG2E 1.4426950408889634f

__device__ __forceinline__ float fexp2(float x){ return __builtin_amdgcn_exp2f(x); }
__device__ __forceinline__ float frcp(float x){ return __builtin_amdgcn_rcpf(x); }
__device__ __forceinline__ float fsigmoid(float x){ return frcp(1.0f + fexp2(-LOG2E*x)); }
__device__ __forceinline__ float ftanh(float x){
    float u = fexp2(2.0f*LOG2E*x);
    return 1.0f - 2.0f*frcp(1.0f + u);
}
__device__ __forceinline__ unsigned rne_bf16(float f){
    unsigned u = __float_as_uint(f);
    return (u + 0x7fffu + ((u >> 16) & 1u)) >> 16;
}
__device__ __forceinline__ unsigned pack2(float lo, float hi){
    return rne_bf16(lo) | (rne_bf16(hi) << 16);
}
__device__ __forceinline__ float bflo(unsigned q){ return __uint_as_float(q << 16); }
__device__ __forceinline__ float bfhi(unsigned q){ return __uint_as_float(q & 0xffff0000u); }

// ---------------------------------------------------------------------------
// k_prep: G = fc_w[0:128]@dec_k packed to bf16 pairs (uint4 of 8 k-values) in
// the exact LDS layout k_dec wants; gy = fc_w[128]@dec_k; gb = fc_b@dec_k+dec_b
// ---------------------------------------------------------------------------
__global__ __launch_bounds__(256) void k_prep(const float* __restrict__ fc_w,
                                              const float* __restrict__ fc_b,
                                              const float* __restrict__ dec_k,
                                              const float* __restrict__ dec_b,
                                              unsigned* __restrict__ Gp,
                                              float* __restrict__ gy,
                                              float* __restrict__ gb){
    int blk = blockIdx.x, tid = threadIdx.x;
    int u0 = tid, u1 = tid + 256;
    if (blk < 16){
        float a0[8], a1[8];
        #pragma unroll
        for (int r = 0; r < 8; ++r){ a0[r] = 0.f; a1[r] = 0.f; }
        for (int m = 0; m < 128; ++m){
            float d0 = dec_k[m*G4 + u0], d1 = dec_k[m*G4 + u1];
            #pragma unroll
            for (int r = 0; r < 8; ++r){
                float w = fc_w[(blk*8 + r)*HH + m];
                a0[r] += w * d0; a1[r] += w * d1;
            }
        }
        #pragma unroll
        for (int c = 0; c < 4; ++c){
            Gp[(blk*G4 + u0)*4 + c] = pack2(a0[2*c], a0[2*c+1]);
            Gp[(blk*G4 + u1)*4 + c] = pack2(a1[2*c], a1[2*c+1]);
        }
    } else if (blk == 16){
        float a0 = 0.f, a1 = 0.f;
        for (int m = 0; m < 128; ++m){
            float w = fc_w[128*HH + m];
            a0 += w * dec_k[m*G4 + u0]; a1 += w * dec_k[m*G4 + u1];
        }
        gy[u0] = a0; gy[u1] = a1;
    } else {
        float a0 = 0.f, a1 = 0.f;
        for (int m = 0; m < 128; ++m){
            float w = fc_b[m];
            a0 += w * dec_k[m*G4 + u0]; a1 += w * dec_k[m*G4 + u1];
        }
        gb[u0] = a0 + dec_b[u0]; gb[u1] = a1 + dec_b[u1];
    }
}

// ---------------------------------------------------------------------------
// k_enc: 512 threads, 1 gate-unit/thread. regs: wa[64] (att W1hs) + ra[128]
// (enc_r col). LDS: enc_k float4 [f4][u], XPJT (x-proj, [j][f] pad 33), XIN.
// ---------------------------------------------------------------------------
__global__ __launch_bounds__(512, 2) void k_enc(const float* __restrict__ inputs,
                                                const float* __restrict__ enc_k,
                                                const float* __restrict__ enc_r,
                                                const float* __restrict__ enc_b,
                                                const float* __restrict__ ae_w1,
                                                const float* __restrict__ ae_b1,
                                                const float* __restrict__ ae_w2,
                                                float* __restrict__ ws_xenc){
    extern __shared__ float lds[];
    float4* KL4  = (float4*)lds;          // [8][512] float4   (16384 words)
    float*  XPJT = lds + 16384;           // [128][33]         (4224)
    float*  XIN  = lds + 20608;           // [96][32]          (3072)
    float*  HST  = lds + 23680;           // 256: h, s
    float*  PP   = lds + 23936;           // 512 partials / z
    float*  PE   = lds + 24448;           // 128
    float*  XT   = lds + 24576;           // 32
    float*  W2E  = lds + 24608;           // 128
    float*  AB1E = lds + 24736;           // 128

    const int b = blockIdx.x, tid = threadIdx.x;
    const int u = tid, j7 = tid & 127, seg = tid >> 7;
    const float* xin_g = inputs + b*TT*FF;

    for (int i = tid; i < TT*FF; i += 512) XIN[i] = xin_g[i];
    for (int i = tid; i < 8*G4; i += 512){
        int f4 = i >> 9, uu = i & 511;
        float4 v;
        v.x = enc_k[(f4*4+0)*G4 + uu];
        v.y = enc_k[(f4*4+1)*G4 + uu];
        v.z = enc_k[(f4*4+2)*G4 + uu];
        v.w = enc_k[(f4*4+3)*G4 + uu];
        KL4[i] = v;
    }
    if (tid < 128){ W2E[tid] = ae_w2[tid]; AB1E[tid] = ae_b1[tid]; }
    if (tid < 256) HST[tid] = 0.f;

    float wa[64], ra[128];
    #pragma unroll
    for (int kk = 0; kk < 64; ++kk) wa[kk] = ae_w1[(seg*64 + kk)*HH + j7];
    #pragma unroll
    for (int k = 0; k < 128; ++k) ra[k] = enc_r[k*G4 + u];
    const float eb = enc_b[u];

    __syncthreads();

    // XPJT[j][f] = sum_t x[t][f] * ae_w1[(256+t)*128 + j]  (time-invariant)
    {
        int j = tid & 127, fh = tid >> 7;
        float acc[8];
        #pragma unroll
        for (int i = 0; i < 8; ++i) acc[i] = 0.f;
        for (int t = 0; t < TT; ++t){
            float w = ae_w1[(256 + t)*HH + j];
            #pragma unroll
            for (int i = 0; i < 8; ++i) acc[i] += XIN[t*FF + fh*8 + i] * w;
        }
        #pragma unroll
        for (int i = 0; i < 8; ++i) XPJT[j*33 + fh*8 + i] = acc[i];
    }
    __syncthreads();

    for (int t = 0; t < TT; ++t){
        // PH-A: attention projection partials over [h;s]
        {
            float a = 0.f;
            #pragma unroll
            for (int kk = 0; kk < 64; kk += 4){
                float4 h4 = *(const float4*)&HST[seg*64 + kk];
                a += h4.x*wa[kk] + h4.y*wa[kk+1] + h4.z*wa[kk+2] + h4.w*wa[kk+3];
            }
            PP[tid] = a;
        }
        __syncthreads();
        if (tid < 128) PE[tid] = PP[tid] + PP[128+tid] + PP[256+tid] + PP[384+tid] + AB1E[tid];
        __syncthreads();
        // PH-B: e[f] partials
        {
            int f = tid & 31, jg = tid >> 5;
            float acc = 0.f;
            #pragma unroll
            for (int i = 0; i < 8; ++i){
                int j = jg*8 + i;
                acc += ftanh(PE[j] + XPJT[j*33 + f]) * W2E[j];
            }
            PP[tid] = acc;
        }
        __syncthreads();
        // reduce + softmax + x_tilde on first 32 lanes
        if (tid < 32){
            float e = 0.f;
            #pragma unroll
            for (int g = 0; g < 16; ++g) e += PP[g*32 + tid];
            float m = e;
            #pragma unroll
            for (int d = 16; d; d >>= 1) m = fmaxf(m, __shfl_xor(m, d, 32));
            float p = fexp2((e - m)*LOG2E);
            float ss = p;
            #pragma unroll
            for (int d = 16; d; d >>= 1) ss += __shfl_xor(ss, d, 32);
            XT[tid] = p * frcp(ss) * XIN[t*FF + tid];
        }
        __syncthreads();
        // PH-D: z[u] = enc_b + x_tilde@enc_k + h@enc_r
        {
            float z = eb;
            #pragma unroll
            for (int f4 = 0; f4 < 8; ++f4){
                float4 xt4 = *(const float4*)&XT[f4*4];
                float4 kv = KL4[f4*G4 + u];
                z += xt4.x*kv.x + xt4.y*kv.y + xt4.z*kv.z + xt4.w*kv.w;
            }
            #pragma unroll
            for (int kk = 0; kk < 128; kk += 4){
                float4 h4 = *(const float4*)&HST[kk];
                z += h4.x*ra[kk] + h4.y*ra[kk+1] + h4.z*ra[kk+2] + h4.w*ra[kk+3];
            }
            PP[u] = z;
        }
        __syncthreads();
        // gates
        if (tid < 128){
            int j = tid;
            float iv = fsigmoid(PP[j]);
            float fv = fsigmoid(PP[128 + j]);
            float gv = ftanh(PP[256 + j]);
            float ov = fsigmoid(PP[384 + j]);
            float cn = fv * HST[128 + j] + iv * gv;
            float hn = ov * ftanh(cn);
            HST[128 + j] = cn;
            HST[j] = hn;
            ws_xenc[(b*TT + t)*HH + j] = hn;
        }
        __syncthreads();
    }
}

// ---------------------------------------------------------------------------
// k_xept: xeptT[b][j][t] = sum_k x_enc[b][t][k] * ad_w1[(256+k)*128 + j]
// ---------------------------------------------------------------------------
__global__ __launch_bounds__(256) void k_xept(const float* __restrict__ ws_xenc,
                                              const float* __restrict__ ad_w1,
                                              float* __restrict__ ws_xept){
    int b = blockIdx.x, q = blockIdx.y, tid = threadIdx.x;
    int j = tid & 127, th = tid >> 7;
    const float* xb = ws_xenc + b*TT*HH;
    float acc[12];
    #pragma unroll
    for (int i = 0; i < 12; ++i) acc[i] = 0.f;
    for (int k = 0; k < 128; ++k){
        float w = ad_w1[(256 + k)*HH + j];
        #pragma unroll
        for (int i = 0; i < 12; ++i){
            int tp = q*24 + th*12 + i;
            acc[i] += xb[tp*HH + k] * w;
        }
    }
    #pragma unroll
    for (int i = 0; i < 12; ++i){
        int tp = q*24 + th*12 + i;
        ws_xept[(b*HH + j)*TT + tp] = acc[i];
    }
}

// ---------------------------------------------------------------------------
// k_dec: 512 threads, 1 gate-unit/thread. regs: ra[128] (dec_r col, fp32) +
// wdc[64] (att W1dc quarter). LDS: G bf16 [k8][u] uint4, x_enc bf16 [t8][k].
// ---------------------------------------------------------------------------
__global__ __launch_bounds__(512, 2) void k_dec(const float* __restrict__ inputs,
                                                const float* __restrict__ dec_r,
                                                const float* __restrict__ ad_w1,
                                                const float* __restrict__ ad_b1,
                                                const float* __restrict__ ad_w2,
                                                const float* __restrict__ ff_w,
                                                const float* __restrict__ ff_b,
                                                const unsigned* __restrict__ Gp,
                                                const float* __restrict__ gy,
                                                const float* __restrict__ gb,
                                                const float* __restrict__ ws_xenc,
                                                const float* __restrict__ ws_xept,
                                                float* __restrict__ out){
    extern __shared__ float lds[];
    uint4*  G8  = (uint4*)lds;              // [16][512] uint4  (32768 words)
    uint4*  XE4 = (uint4*)(lds + 32768);    // [12][128] uint4  (6144 words)
    float*  DST = lds + 38912;              // 256: d, c
    float*  PP  = lds + 39168;              // 512 partials / z
    float*  APJ = lds + 39680;              // 128
    float*  BETA= lds + 39808;              // 128 (96 used, unnormalized)
    float*  CTX = lds + 39936;              // 128
    float*  W2L = lds + 40064;              // 128
    float*  SCAL= lds + 40192;              // 8: [0]=1/sum, [1]=y_t

    const int b = blockIdx.x, tid = threadIdx.x;
    const int u = tid, j7 = tid & 127, seg = tid >> 7;

    {
        unsigned* Gs = (unsigned*)G8;
        for (int i = tid; i < 16*G4*4; i += 512) Gs[i] = Gp[i];
    }
    {
        const float* xe_g = ws_xenc + b*TT*HH;
        for (int i = tid; i < 12*HH; i += 512){
            int t8 = i >> 7, k = i & 127;
            float x0 = xe_g[(t8*8+0)*HH + k], x1 = xe_g[(t8*8+1)*HH + k];
            float x2 = xe_g[(t8*8+2)*HH + k], x3 = xe_g[(t8*8+3)*HH + k];
            float x4 = xe_g[(t8*8+4)*HH + k], x5 = xe_g[(t8*8+5)*HH + k];
            float x6 = xe_g[(t8*8+6)*HH + k], x7 = xe_g[(t8*8+7)*HH + k];
            uint4 qq;
            qq.x = pack2(x0,x1); qq.y = pack2(x2,x3);
            qq.z = pack2(x4,x5); qq.w = pack2(x6,x7);
            XE4[i] = qq;
        }
    }
    if (tid < 128) W2L[tid] = ad_w2[tid];
    if (tid < 256) DST[tid] = 0.f;

    float ra[128], wdc[64];
    #pragma unroll
    for (int k = 0; k < 128; ++k) ra[k] = dec_r[k*G4 + u];
    #pragma unroll
    for (int kk = 0; kk < 64; ++kk) wdc[kk] = ad_w1[(seg*64 + kk)*HH + j7];
    const float gbr = gb[u], gyr = gy[u];
    const float ab1 = (tid < 128) ? ad_b1[tid] : 0.f;

    __syncthreads();

    const float* xeptb = ws_xept + b*HH*TT;

    for (int t = 0; t < TT; ++t){
        if (tid == 0) SCAL[1] = inputs[b*TT*FF + t*FF + (FF-1)];
        // PH-1: attention projection partials over [d;c]
        {
            float a = 0.f;
            #pragma unroll
            for (int kk = 0; kk < 64; kk += 4){
                float4 d4 = *(const float4*)&DST[seg*64 + kk];
                a += d4.x*wdc[kk] + d4.y*wdc[kk+1] + d4.z*wdc[kk+2] + d4.w*wdc[kk+3];
            }
            PP[tid] = a;
        }
        // PH-5a: z from d@dec_r (register column; only needs DST)
        float z = gbr;
        #pragma unroll
        for (int kk = 0; kk < 128; kk += 4){
            float4 d4 = *(const float4*)&DST[kk];
            z += d4.x*ra[kk] + d4.y*ra[kk+1] + d4.z*ra[kk+2] + d4.w*ra[kk+3];
        }
        __syncthreads();
        if (tid < 128) APJ[tid] = PP[tid] + PP[128+tid] + PP[256+tid] + PP[384+tid] + ab1;
        __syncthreads();
        // PH-2: e[t'] partials (4 j-chunks of 32)
        {
            int tp = tid & 127, jh = tid >> 7;
            float acc = 0.f;
            if (tp < TT){
                const float* xrow = xeptb + (jh*32)*TT + tp;
                #pragma unroll
                for (int jj = 0; jj < 32; ++jj){
                    int j = jh*32 + jj;
                    acc += ftanh(APJ[j] + xrow[jj*TT]) * W2L[j];
                }
            }
            PP[tid] = acc;
        }
        __syncthreads();
        // reduce + softmax over 96 on wave 0
        if (tid < 64){
            float ea = PP[tid] + PP[128+tid] + PP[256+tid] + PP[384+tid];
            float ebv = -3.0e38f;
            if (tid < 32) ebv = PP[64+tid] + PP[192+tid] + PP[320+tid] + PP[448+tid];
            float m = fmaxf(ea, ebv);
            #pragma unroll
            for (int d = 32; d; d >>= 1) m = fmaxf(m, __shfl_xor(m, d, 64));
            float pa = fexp2((ea - m)*LOG2E);
            float pb = (tid < 32) ? fexp2((ebv - m)*LOG2E) : 0.f;
            float ss = pa + pb;
            #pragma unroll
            for (int d = 32; d; d >>= 1) ss += __shfl_xor(ss, d, 64);
            BETA[tid] = pa;
            if (tid < 32) BETA[64 + tid] = pb;
            if (tid == 0) SCAL[0] = frcp(ss);
        }
        __syncthreads();
        // PH-4: ctx partials from bf16 x_enc
        {
            int k = tid & 127, th = tid >> 7;
            float a = 0.f;
            #pragma unroll
            for (int i = 0; i < 3; ++i){
                int t8 = th*3 + i;
                uint4 qq = XE4[t8*HH + k];
                float4 b0 = *(const float4*)&BETA[t8*8];
                float4 b1 = *(const float4*)&BETA[t8*8 + 4];
                a += b0.x*bflo(qq.x) + b0.y*bfhi(qq.x)
                   + b0.z*bflo(qq.y) + b0.w*bfhi(qq.y)
                   + b1.x*bflo(qq.z) + b1.y*bfhi(qq.z)
                   + b1.z*bflo(qq.w) + b1.w*bfhi(qq.w);
            }
            PP[tid] = a;
        }
        __syncthreads();
        if (tid < 128) CTX[tid] = (PP[tid] + PP[128+tid] + PP[256+tid] + PP[384+tid]) * SCAL[0];
        __syncthreads();
        // PH-5b: z += y*gy + ctx@G (bf16 G, b128 LDS reads)
        {
            float yt = SCAL[1];
            z += yt * gyr;
            #pragma unroll
            for (int k8 = 0; k8 < 16; ++k8){
                uint4 g = G8[k8*G4 + u];
                float4 c0 = *(const float4*)&CTX[k8*8];
                float4 c1 = *(const float4*)&CTX[k8*8 + 4];
                z += c0.x*bflo(g.x) + c0.y*bfhi(g.x)
                   + c0.z*bflo(g.y) + c0.w*bfhi(g.y)
                   + c1.x*bflo(g.z) + c1.y*bfhi(g.z)
                   + c1.z*bflo(g.w) + c1.w*bfhi(g.w);
            }
            PP[u] = z;
        }
        __syncthreads();
        // PH-6: gates
        if (tid < 128){
            int j = tid;
            float iv = fsigmoid(PP[j]);
            float fv = fsigmoid(PP[128 + j]);
            float gv = ftanh(PP[256 + j]);
            float ov = fsigmoid(PP[384 + j]);
            float cn = fv * DST[128 + j] + iv * gv;
            float hn = ov * ftanh(cn);
            DST[128 + j] = cn;
            DST[j] = hn;
        }
        __syncthreads();
    }

    // output: y_pred = [d_n, ctx] @ ff_w + ff_b
    {
        int jp = tid & 31, sg = tid >> 5;
        float a = 0.f;
        #pragma unroll
        for (int kk = 0; kk < 16; ++kk){
            int k = sg*16 + kk;
            float val = (k < 128) ? DST[k] : CTX[k - 128];
            a += val * ff_w[k*FF + jp];
        }
        PP[sg*32 + jp] = a;
    }
    __syncthreads();
    if (tid < 32){
        float o = ff_b[tid];
        #pragma unroll
        for (int s = 0; s < 16; ++s) o += PP[s*32 + tid];
        out[b*FF + tid] = o;
    }
}

// ---------------------------------------------------------------------------
extern "C" void kernel_launch(void* const* d_in, const int* in_sizes, int n_in,
                              void* d_out, int out_size, void* d_ws, size_t ws_size,
                              hipStream_t stream) {
    const float* inputs = (const float*)d_in[0];
    const float* enc_k  = (const float*)d_in[1];
    const float* enc_r  = (const float*)d_in[2];
    const float* enc_b  = (const float*)d_in[3];
    const float* ae_w1  = (const float*)d_in[4];
    const float* ae_b1  = (const float*)d_in[5];
    const float* ae_w2  = (const float*)d_in[6];
    // d_in[7] = ae_b2 (softmax-invariant, unused)
    const float* dec_k  = (const float*)d_in[8];
    const float* dec_r  = (const float*)d_in[9];
    const float* dec_b  = (const float*)d_in[10];
    const float* ad_w1  = (const float*)d_in[11];
    const float* ad_b1  = (const float*)d_in[12];
    const float* ad_w2  = (const float*)d_in[13];
    // d_in[14] = ad_b2 (softmax-invariant, unused)
    const float* fc_w   = (const float*)d_in[15];
    const float* fc_b   = (const float*)d_in[16];
    const float* ff_w   = (const float*)d_in[17];
    const float* ff_b   = (const float*)d_in[18];

    float* ws      = (float*)d_ws;
    float* ws_xenc = ws;                         // 64*96*128 floats
    float* ws_xept = ws + 786432;                // 64*128*96 floats
    unsigned* Gp   = (unsigned*)(ws + 1572864);  // 32768 uints
    float* gy      = ws + 1605632;               // 512
    float* gb      = ws + 1606144;               // 512

    hipFuncSetAttribute((const void*)k_enc, hipFuncAttributeMaxDynamicSharedMemorySize, 99456);
    hipFuncSetAttribute((const void*)k_dec, hipFuncAttributeMaxDynamicSharedMemorySize, 160800);

    k_prep<<<18, 256, 0, stream>>>(fc_w, fc_b, dec_k, dec_b, Gp, gy, gb);
    k_enc<<<64, 512, 99456, stream>>>(inputs, enc_k, enc_r, enc_b, ae_w1, ae_b1, ae_w2, ws_xenc);
    k_xept<<<dim3(64, 4), 256, 0, stream>>>(ws_xenc, ad_w1, ws_xept);
    k_dec<<<64, 512, 160800, stream>>>(inputs, dec_r, ad_w1, ad_b1, ad_w2, ff_w, ff_b,
                                       Gp, gy, gb, ws_xenc, ws_xept, (float*)d_out);
}